// Round 12
// baseline (12902.448 us; speedup 1.0000x reference)
//
#include <hip/hip_runtime.h>

typedef _Float16 h2f __attribute__((ext_vector_type(2)));

#define LOG2E 1.44269504088896f

__device__ __forceinline__ float fexp2(float x){ return __builtin_amdgcn_exp2f(x); }
__device__ __forceinline__ float frcp (float x){ return __builtin_amdgcn_rcpf(x); }
__device__ __forceinline__ float sigm (float x){ return frcp(1.f + fexp2(-LOG2E*x)); }
__device__ __forceinline__ float tanhf2(float x){
  x = fminf(15.f, fmaxf(-15.f, x));
  float e = fexp2(2.f*LOG2E*x);
  return (e-1.f)*frcp(e+1.f);
}
__device__ __forceinline__ unsigned pkh2(float a, float b){
  h2f h; h.x = (_Float16)a; h.y = (_Float16)b;
  return __builtin_bit_cast(unsigned, h);
}

#if __has_builtin(__builtin_amdgcn_fdot2)
__device__ __forceinline__ float dot2(unsigned a, unsigned b, float c){
  return __builtin_amdgcn_fdot2(__builtin_bit_cast(h2f,a), __builtin_bit_cast(h2f,b), c, false);
}
#else
__device__ __forceinline__ float dot2(unsigned a, unsigned b, float c){
  h2f ha=__builtin_bit_cast(h2f,a), hb=__builtin_bit_cast(h2f,b);
  return c + (float)ha.x*(float)hb.x + (float)ha.y*(float)hb.y;
}
#endif

__device__ __forceinline__ void dot8_2(uint4 w, uint4 x, float& a0, float& a1){
  a0 = dot2(w.x, x.x, a0); a1 = dot2(w.y, x.y, a1);
  a0 = dot2(w.z, x.z, a0); a1 = dot2(w.w, x.w, a1);
}

// simple matvec (prep kernels)
template<int N, int K8>
__device__ __forceinline__ float mv(const uint4* __restrict__ W, const uint4* __restrict__ xs, int n){
  float a0 = 0.f, a1 = 0.f;
  #pragma unroll 4
  for (int k8 = 0; k8 < K8; ++k8)
    dot8_2(W[k8*N + n], xs[k8], a0, a1);
  return a0 + a1;
}

// chunked single-elem (mel kernel)
template<int N, int K8, int C>
__device__ __forceinline__ float mvc(const uint4* __restrict__ W, const uint4* __restrict__ xs, int n){
  float a0 = 0.f, a1 = 0.f;
  #pragma unroll 1
  for (int k8 = 0; k8 + C <= K8; k8 += C){
    uint4 w[C];
    #pragma unroll
    for (int i = 0; i < C; ++i) w[i] = W[(size_t)(k8+i)*N + n];
    #pragma unroll
    for (int i = 0; i < C; ++i) dot8_2(w[i], xs[k8+i], a0, a1);
  }
  return a0 + a1;
}

// DUAL-batch chunked matvec: weight uint4 loaded ONCE, dotted with both
// elements' activation vectors (the k=2 amortization). Requires C | K8.
template<int N, int K8, int C>
__device__ __forceinline__ void mvc2(const uint4* __restrict__ W,
    const uint4* __restrict__ xs0, const uint4* __restrict__ xs1, int n,
    float& o0, float& o1){
  float a0=0.f, b0=0.f, a1=0.f, b1=0.f;
  #pragma unroll 1
  for (int k8 = 0; k8 < K8; k8 += C){
    uint4 w[C];
    #pragma unroll
    for (int i = 0; i < C; ++i) w[i] = W[(size_t)(k8+i)*N + n];
    #pragma unroll
    for (int i = 0; i < C; ++i){
      dot8_2(w[i], xs0[k8+i], a0, b0);
      dot8_2(w[i], xs1[k8+i], a1, b1);
    }
  }
  o0 = a0 + b0; o1 = a1 + b1;
}

// ---------------- workspace layout (bytes) ----------------
static constexpr size_t OFF_W1   = 0;          // 256x400
static constexpr size_t OFF_W2   = 204800;     // 128x256
static constexpr size_t OFF_WIHA = 270336;     // 768x384
static constexpr size_t OFF_WHHA = 860160;     // 768x256
static constexpr size_t OFF_WQ   = 1253376;    // 256x256
static constexpr size_t OFF_WP   = 1384448;    // 256x512
static constexpr size_t OFF_WD1I = 1646592;    // 768x256
static constexpr size_t OFF_WD1H = 2039808;
static constexpr size_t OFF_WD2I = 2433024;
static constexpr size_t OFF_WD2H = 2826240;
static constexpr size_t OFF_WMEL = 3219456;    // 400x256
static constexpr size_t OFF_WM   = 3424256;    // 256x256
static constexpr size_t OFF_TPM  = 3555328;    // tanh(pm) GATHERED: uint4[b][g=32][t=512], g=4 d2's
static constexpr size_t OFF_ENCH = 37109760;   // enc f16 [b][t][d2] (uint4 view = [b][t][g])

// ---------------- prep kernels ----------------
__global__ void pack_w(const float* __restrict__ src, uint4* __restrict__ dst, int N, int K8){
  int idx = blockIdx.x*blockDim.x + threadIdx.x;
  if (idx >= N*K8) return;
  int n = idx % N, k8 = idx / N;
  const float* s = src + (size_t)n*(K8*8) + k8*8;
  dst[idx] = make_uint4(pkh2(s[0],s[1]), pkh2(s[2],s[3]), pkh2(s[4],s[5]), pkh2(s[6],s[7]));
}

__global__ void conv_enc(const float* __restrict__ enc, unsigned* __restrict__ encH){
  size_t i = blockIdx.x*(size_t)blockDim.x + threadIdx.x;
  if (i >= (size_t)128*512*128) return;
  const float2 f = *(const float2*)(enc + 2*i);
  encH[i] = pkh2(f.x, f.y);
}

// writes tpm in GATHERED layout: u32 index = ((b*32 + g)*512 + t)*4 + j
// where g = d>>3, j = (d>>1)&3  (uint4 [g][t] holds d2 = 4g..4g+3)
__global__ __launch_bounds__(1024) void pm_kernel(const float* __restrict__ enc,
    const uint4* __restrict__ Wmp, unsigned* __restrict__ tpm)
{
  int b = blockIdx.y, tc = blockIdx.x;
  int tid = threadIdx.x;
  __shared__ __align__(16) unsigned s_e[4][128];
  if (tid < 512){
    int r = tid >> 7, d2 = tid & 127;
    const float2 f = *(const float2*)(enc + ((size_t)b*512 + tc*4 + r)*256 + 2*d2);
    s_e[r][d2] = pkh2(f.x, f.y);
  }
  __syncthreads();
  int d = tid & 255, r = tid >> 8;
  float acc = mv<256,32>(Wmp, (const uint4*)s_e[r], d);
  float tq = tanhf2(acc);
  float hi = __shfl_down(tq, 1);
  if ((d & 1) == 0){
    int t = tc*4 + r;
    tpm[ (((size_t)b*32 + (d>>3))*512 + t)*4 + ((d>>1)&3) ] = pkh2(tq, hi);
  }
}

// Prenet hoisted: pre2(t,b) stashed in alignments slot (first 64 u32 of
// out_align[b][t]); decoder reads at P1(t), softmax overwrites same step.
__global__ __launch_bounds__(256) void prenet_kernel(
    const float* __restrict__ inputs,
    const float* __restrict__ b1, const float* __restrict__ b2,
    const uint4* __restrict__ W1p, const uint4* __restrict__ W2p,
    float* __restrict__ out)
{
  int t = blockIdx.x, b = blockIdx.y;
  int tid = threadIdx.x;
  __shared__ __align__(16) unsigned s_x[200];
  __shared__ __align__(16) unsigned s_p1[128];
  __shared__ float s_a[256];
  if (tid < 200){
    unsigned xv = 0u;
    if (t > 0){
      const float2 f = *(const float2*)(inputs + (size_t)b*80000 + (size_t)(t-1)*400 + 2*tid);
      xv = pkh2(f.x, f.y);
    }
    s_x[tid] = xv;
  }
  __syncthreads();
  float a = fmaxf(mv<256,50>(W1p, (const uint4*)s_x, tid) + b1[tid], 0.f);
  s_a[tid] = a;
  __syncthreads();
  if (tid < 128) s_p1[tid] = pkh2(s_a[2*tid], s_a[2*tid+1]);
  __syncthreads();
  if (tid < 128){
    float p = fmaxf(mv<128,32>(W2p, (const uint4*)s_p1, tid) + b2[tid], 0.f);
    float pN = __shfl_down(p, 1);
    if (!(tid & 1)){
      unsigned* dst = (unsigned*)(out + (size_t)10240000 + ((size_t)b*200 + t)*512);
      dst[tid>>1] = pkh2(p, pN);
    }
  }
}

// Mel hoisted: decoder left packed dec_in at out_mel[b][t][0:128] (u32);
// overwrite slot with the 400 mel floats.
__global__ __launch_bounds__(512) void mel_kernel(
    const float* __restrict__ bmel, const uint4* __restrict__ Wmelp,
    float* __restrict__ out)
{
  int t = blockIdx.x, b = blockIdx.y;
  int tid = threadIdx.x;
  __shared__ __align__(16) unsigned s_d[128];
  float* po = out + ((size_t)b*200 + t)*400;
  if (tid < 128) s_d[tid] = ((const unsigned*)po)[tid];
  __syncthreads();
  if (tid < 400){
    float r = mvc<400,32,8>(Wmelp, (const uint4*)s_d, tid) + bmel[tid];
    __builtin_nontemporal_store(r, &po[tid]);
  }
}

// ---------------- decoder (k=2: 64 WGs, 2 batch elems each) ----------------
// Weight loads shared across the 2 elems (mvc2) -> weight stream per output
// elem halves. Per-step barrier/latency overhead amortized over 2 elems.
// All chunk buffers call-local, C=8, no cross-barrier register carry.
__global__ __launch_bounds__(1024, 1) void decoder(
   const float* __restrict__ biha, const float* __restrict__ bhha,
   const float* __restrict__ vvec, const float* __restrict__ bp,
   const float* __restrict__ bd1i, const float* __restrict__ bd1h,
   const float* __restrict__ bd2i, const float* __restrict__ bd2h,
   const uint4* __restrict__ Wihap, const uint4* __restrict__ Whhap,
   const uint4* __restrict__ Wqp, const uint4* __restrict__ Wpp,
   const uint4* __restrict__ Wd1ip, const uint4* __restrict__ Wd1hp,
   const uint4* __restrict__ Wd2ip, const uint4* __restrict__ Wd2hp,
   const unsigned* __restrict__ tpm, const unsigned* __restrict__ encH,
   float* __restrict__ out)
{
  const int tid = threadIdx.x;
  const int b0 = 2*blockIdx.x, b1v = b0 + 1;

  __shared__ __align__(16) unsigned s_cin2[2][192]; // [pre2(64) | ctx(128)]
  __shared__ __align__(16) unsigned s_cat2[2][256]; // [attn_h(128) | ctx(128)]
  __shared__ __align__(16) unsigned s_di2[2][128];
  __shared__ __align__(16) unsigned s_h12[2][128];
  __shared__ __align__(16) unsigned s_h22[2][128];
  __shared__ float  s_gha[2][768], s_gh1[2][768], s_gh2[2][768];
  __shared__ float  s_g[2][768];
  __shared__ float  s_ahf[2][256], s_h1f[2][256], s_h2f[2][256];
  __shared__ float  s_dif[2][256];
  __shared__ float4 s_tv[2][128];     // {tq[2d2], tq[2d2+1], v[2d2], v[2d2+1]}
  __shared__ float  s_lp[2][512];
  __shared__ float2 s_cp[2][16][32][4]; // [be][ts][g][j] ctx partials
  __shared__ float  s_mvp[2][4][256];
  __shared__ float  s_align[2][512];
  __shared__ float  s_red[2][8];

  if (tid < 384){ int be=tid/192, i=tid%192; s_cin2[be][i] = 0u; }
  if (tid < 512){ int be=tid>>8, i=tid&255;
    s_cat2[be][i]=0u; s_ahf[be][i]=0.f; s_h1f[be][i]=0.f; s_h2f[be][i]=0.f; }
  if (tid < 256){ int be=tid>>7, i=tid&127;
    s_h12[be][i]=0u; s_h22[be][i]=0u;
    s_tv[be][i].z = vvec[2*i]; s_tv[be][i].w = vvec[2*i+1]; }
  __syncthreads();

  const unsigned* encB[2] = { encH + (size_t)b0*65536, encH + (size_t)b1v*65536 };
  const uint4*    tpm4[2] = { (const uint4*)tpm + (size_t)b0*16384,
                              (const uint4*)tpm + (size_t)b1v*16384 };
  float* outMel[2] = { out + (size_t)b0*80000, out + (size_t)b1v*80000 };
  float* outAl [2] = { out + 10240000ull + (size_t)b0*102400,
                       out + 10240000ull + (size_t)b1v*102400 };

  const uint4* cin4[2] = { (const uint4*)s_cin2[0], (const uint4*)s_cin2[1] };
  const uint4* cat4[2] = { (const uint4*)s_cat2[0], (const uint4*)s_cat2[1] };
  const uint4* di4 [2] = { (const uint4*)s_di2[0],  (const uint4*)s_di2[1]  };
  const uint4* h14 [2] = { (const uint4*)s_h12[0],  (const uint4*)s_h12[1]  };
  const uint4* h24 [2] = { (const uint4*)s_h22[0],  (const uint4*)s_h22[1]  };

  for (int t = 0; t < 200; ++t){
    // ===== P1: gha[768] dual || gh2 rows 0..191 dual || pre2 load (2x64)
    if (tid < 768){
      float o0,o1; mvc2<768,32,8>(Whhap, cat4[0], cat4[1], tid, o0, o1);
      s_gha[0][tid] = o0 + bhha[tid]; s_gha[1][tid] = o1 + bhha[tid];
    } else if (tid < 960){
      int r = tid - 768;
      float o0,o1; mvc2<768,32,8>(Wd2hp, h24[0], h24[1], r, o0, o1);
      s_gh2[0][r] = o0 + bd2h[r]; s_gh2[1][r] = o1 + bd2h[r];
    } else {
      int j = tid - 960;
      s_cin2[0][j] = ((const unsigned*)(outAl[0] + (size_t)t*512))[j];
      s_cin2[1][j] = ((const unsigned*)(outAl[1] + (size_t)t*512))[j];
    }
    __syncthreads();
    // ===== P2: gh1[768] dual || gh2 rows 192..447 dual
    if (tid < 768){
      float o0,o1; mvc2<768,32,8>(Wd1hp, h14[0], h14[1], tid, o0, o1);
      s_gh1[0][tid] = o0 + bd1h[tid]; s_gh1[1][tid] = o1 + bd1h[tid];
    } else {
      int r = 192 + tid - 768;
      float o0,o1; mvc2<768,32,8>(Wd2hp, h24[0], h24[1], r, o0, o1);
      s_gh2[0][r] = o0 + bd2h[r]; s_gh2[1][r] = o1 + bd2h[r];
    }
    __syncthreads();
    // ===== P3: gi_a[768] dual (K8=48) || gh2 rows 448..703 dual
    if (tid < 768){
      float o0,o1; mvc2<768,48,8>(Wihap, cin4[0], cin4[1], tid, o0, o1);
      o0 += biha[tid]; o1 += biha[tid];
      if (tid < 512){ s_g[0][tid] = sigm(o0 + s_gha[0][tid]); s_g[1][tid] = sigm(o1 + s_gha[1][tid]); }
      else          { s_g[0][tid] = o0;                        s_g[1][tid] = o1; }
    } else {
      int r = 448 + tid - 768;
      float o0,o1; mvc2<768,32,8>(Wd2hp, h24[0], h24[1], r, o0, o1);
      s_gh2[0][r] = o0 + bd2h[r]; s_gh2[1][r] = o1 + bd2h[r];
    }
    __syncthreads();
    // ===== GA: attn-GRU gates (2x256) || gh2 rows 704..767 dual
    if (tid < 512){
      int be = tid>>8, i = tid&255;
      float rr = s_g[be][i], z = s_g[be][256+i];
      float nv = tanhf2(s_g[be][512+i] + rr*s_gha[be][512+i]);
      float h  = nv + z*(s_ahf[be][i] - nv);
      s_ahf[be][i] = h;
      float hN = __shfl_down(h, 1);
      if (!(i&1)) s_cat2[be][i>>1] = pkh2(h, hN);
    } else if (tid < 576){
      int r = 704 + tid - 512;
      float o0,o1; mvc2<768,32,8>(Wd2hp, h24[0], h24[1], r, o0, o1);
      s_gh2[0][r] = o0 + bd2h[r]; s_gh2[1][r] = o1 + bd2h[r];
    }
    __syncthreads();
    // ===== P4: q = Wq@attn_h (split-K4, dual)
    {
      int n = tid & 255, p = (tid>>8)&3;
      float o0,o1; mvc2<256,8,8>(Wqp + (size_t)p*8*256, cat4[0]+p*8, cat4[1]+p*8, n, o0, o1);
      s_mvp[0][p][n] = o0; s_mvp[1][p][n] = o1;
    }
    __syncthreads();
    // ===== QT: tanh(q) (2x256)
    if (tid < 512){
      int be = tid>>8, i = tid&255;
      float q = s_mvp[be][0][i]+s_mvp[be][1][i]+s_mvp[be][2][i]+s_mvp[be][3][i];
      ((float*)&s_tv[be][i>>1])[i&1] = tanhf2(q);
    }
    __syncthreads();
    // ===== P5: logits, tanh-sum identity; gathered uint4 (lane-dense), pairwise rcp
    {
      int be = tid>>9, tt = tid&511;
      const uint4* tp = tpm4[be] + tt;
      float acc = 0.f;
      #pragma unroll 1
      for (int g = 0; g < 32; g += 8){
        uint4 T[8];
        #pragma unroll
        for (int i = 0; i < 8; ++i) T[i] = tp[(size_t)(g+i)*512];
        #pragma unroll
        for (int i = 0; i < 8; ++i){
          #pragma unroll
          for (int j = 0; j < 4; ++j){
            unsigned u = ((const unsigned*)&T[i])[j];
            h2f ta = __builtin_bit_cast(h2f, u);
            float4 tv = s_tv[be][(g+i)*4 + j];
            float ta0 = (float)ta.x, ta1 = (float)ta.y;
            float n0 = ta0 + tv.x, n1 = ta1 + tv.y;
            float d0 = fmaf(ta0, tv.x, 1.f), d1 = fmaf(ta1, tv.y, 1.f);
            float r  = frcp(d0*d1);
            acc = fmaf(fmaf(tv.w*n1, d0, (tv.z*n0)*d1), r, acc);
          }
        }
      }
      s_lp[be][tt] = acc;
    }
    __syncthreads();
    // ===== softmax (no max pass: |logit| <= sum|v| ~ 10.2)
    float ee = 0.f;
    {
      int be = tid>>9, tt = tid&511;
      float lg = s_lp[be][tt];
      ee = fexp2(LOG2E*lg);
      float s = ee;
      #pragma unroll
      for (int off = 32; off >= 1; off >>= 1) s += __shfl_xor(s, off);
      if ((tid & 63) == 0) s_red[be][tt>>6] = s;
    }
    __syncthreads();
    {
      int be = tid>>9, tt = tid&511;
      float S = (s_red[be][0]+s_red[be][1])+(s_red[be][2]+s_red[be][3])
              + (s_red[be][4]+s_red[be][5])+(s_red[be][6]+s_red[be][7]);
      float a = ee * frcp(S);
      s_align[be][tt] = a;
      __builtin_nontemporal_store(a, &outAl[be][(size_t)t*512 + tt]);
    }
    __syncthreads();
    // ===== P6: ctx partials; enc uint4 view [t][g] (lane-dense)
    {
      int be = tid>>9, ts = (tid>>5)&15, g = tid&31;
      const uint4* e4 = (const uint4*)encB[be] + (size_t)(ts*32)*32 + g;
      float2 c0={0,0}, c1={0,0}, c2={0,0}, c3={0,0};
      #pragma unroll 1
      for (int u = 0; u < 32; u += 8){
        uint4 E[8];
        #pragma unroll
        for (int i = 0; i < 8; ++i) E[i] = e4[(size_t)(u+i)*32];
        #pragma unroll
        for (int i = 0; i < 8; ++i){
          float a = s_align[be][ts*32 + u + i];
          h2f e0 = __builtin_bit_cast(h2f, E[i].x);
          h2f e1 = __builtin_bit_cast(h2f, E[i].y);
          h2f e2 = __builtin_bit_cast(h2f, E[i].z);
          h2f e3 = __builtin_bit_cast(h2f, E[i].w);
          c0.x += a*(float)e0.x; c0.y += a*(float)e0.y;
          c1.x += a*(float)e1.x; c1.y += a*(float)e1.y;
          c2.x += a*(float)e2.x; c2.y += a*(float)e2.y;
          c3.x += a*(float)e3.x; c3.y += a*(float)e3.y;
        }
      }
      s_cp[be][ts][g][0] = c0; s_cp[be][ts][g][1] = c1;
      s_cp[be][ts][g][2] = c2; s_cp[be][ts][g][3] = c3;
    }
    __syncthreads();
    // ===== CR: ctx reduce (2x256) + pack
    if (tid < 512){
      int be = tid>>8, d = tid&255;
      int d2 = d>>1, g = d2>>2, j = d2&3, comp = d&1;
      const float* base = (const float*)s_cp + ((size_t)be*16*32*4*2) + (size_t)g*8 + j*2 + comp;
      float c = 0.f;
      #pragma unroll
      for (int ts = 0; ts < 16; ++ts) c += base[(size_t)ts*32*4*2];
      float cN = __shfl_down(c, 1);
      if (!(d&1)){ unsigned pk = pkh2(c, cN); s_cin2[be][64+d2] = pk; s_cat2[be][128+d2] = pk; }
    }
    __syncthreads();
    // ===== P7: dec_in = Wp@cat(attn_h,ctx) (split-K4, dual)
    {
      int n = tid & 255, p = (tid>>8)&3;
      float o0,o1; mvc2<256,16,8>(Wpp + (size_t)p*16*256, cat4[0]+p*16, cat4[1]+p*16, n, o0, o1);
      s_mvp[0][p][n] = o0; s_mvp[1][p][n] = o1;
    }
    __syncthreads();
    // ===== DM (2x256)
    if (tid < 512){
      int be = tid>>8, i = tid&255;
      float di = s_mvp[be][0][i]+s_mvp[be][1][i]+s_mvp[be][2][i]+s_mvp[be][3][i] + bp[i];
      s_dif[be][i] = di;
      float dN = __shfl_down(di, 1);
      if (!(i&1)) s_di2[be][i>>1] = pkh2(di, dN);
    }
    __syncthreads();
    // ===== P8: gi_d1 dual
    if (tid < 768){
      float o0,o1; mvc2<768,32,8>(Wd1ip, di4[0], di4[1], tid, o0, o1);
      o0 += bd1i[tid]; o1 += bd1i[tid];
      if (tid < 512){ s_g[0][tid] = sigm(o0 + s_gh1[0][tid]); s_g[1][tid] = sigm(o1 + s_gh1[1][tid]); }
      else          { s_g[0][tid] = o0;                        s_g[1][tid] = o1; }
    }
    __syncthreads();
    // ===== G1 (2x256)
    if (tid < 512){
      int be = tid>>8, i = tid&255;
      float rr = s_g[be][i], z = s_g[be][256+i];
      float nv = tanhf2(s_g[be][512+i] + rr*s_gh1[be][512+i]);
      float h  = nv + z*(s_h1f[be][i] - nv);
      s_h1f[be][i] = h;
      float di = s_dif[be][i] + h; s_dif[be][i] = di;
      float hN = __shfl_down(h, 1), dN = __shfl_down(di, 1);
      if (!(i&1)){ s_h12[be][i>>1] = pkh2(h, hN); s_di2[be][i>>1] = pkh2(di, dN); }
    }
    __syncthreads();
    // ===== P9: gi_d2 dual
    if (tid < 768){
      float o0,o1; mvc2<768,32,8>(Wd2ip, di4[0], di4[1], tid, o0, o1);
      o0 += bd2i[tid]; o1 += bd2i[tid];
      if (tid < 512){ s_g[0][tid] = sigm(o0 + s_gh2[0][tid]); s_g[1][tid] = sigm(o1 + s_gh2[1][tid]); }
      else          { s_g[0][tid] = o0;                        s_g[1][tid] = o1; }
    }
    __syncthreads();
    // ===== G2 (2x256) + stash packed dec_in for mel post-kernel
    if (tid < 512){
      int be = tid>>8, i = tid&255;
      float rr = s_g[be][i], z = s_g[be][256+i];
      float nv = tanhf2(s_g[be][512+i] + rr*s_gh2[be][512+i]);
      float h  = nv + z*(s_h2f[be][i] - nv);
      s_h2f[be][i] = h;
      float di = s_dif[be][i] + h;
      float hN = __shfl_down(h, 1), dN = __shfl_down(di, 1);
      if (!(i&1)){
        unsigned dpk = pkh2(di, dN);
        s_h22[be][i>>1] = pkh2(h, hN);
        ((unsigned*)(outMel[be] + (size_t)t*400))[i>>1] = dpk;
      }
    }
    __syncthreads();
  }
}

// ---------------- launch ----------------
extern "C" void kernel_launch(void* const* d_in, const int* in_sizes, int n_in,
                              void* d_out, int out_size, void* d_ws, size_t ws_size,
                              hipStream_t stream){
  (void)in_sizes; (void)n_in; (void)out_size; (void)ws_size;
  const float* enc    = (const float*)d_in[0];
  const float* inputs = (const float*)d_in[1];
  const float* W1 = (const float*)d_in[2];   const float* b1 = (const float*)d_in[3];
  const float* W2 = (const float*)d_in[4];   const float* b2 = (const float*)d_in[5];
  const float* Wiha = (const float*)d_in[6]; const float* Whha = (const float*)d_in[7];
  const float* biha = (const float*)d_in[8]; const float* bhha = (const float*)d_in[9];
  const float* Wq = (const float*)d_in[10];  const float* v  = (const float*)d_in[11];
  const float* Wm = (const float*)d_in[12];
  const float* Wp = (const float*)d_in[13];  const float* bp = (const float*)d_in[14];
  const float* Wd1i = (const float*)d_in[15]; const float* Wd1h = (const float*)d_in[16];
  const float* bd1i = (const float*)d_in[17]; const float* bd1h = (const float*)d_in[18];
  const float* Wd2i = (const float*)d_in[19]; const float* Wd2h = (const float*)d_in[20];
  const float* bd2i = (const float*)d_in[21]; const float* bd2h = (const float*)d_in[22];
  const float* Wmel = (const float*)d_in[23]; const float* bmel = (const float*)d_in[24];

  char* ws = (char*)d_ws;
  uint4* W1p   = (uint4*)(ws + OFF_W1);
  uint4* W2p   = (uint4*)(ws + OFF_W2);
  uint4* Wihap = (uint4*)(ws + OFF_WIHA);
  uint4* Whhap = (uint4*)(ws + OFF_WHHA);
  uint4* Wqp   = (uint4*)(ws + OFF_WQ);
  uint4* Wpp   = (uint4*)(ws + OFF_WP);
  uint4* Wd1ip = (uint4*)(ws + OFF_WD1I);
  uint4* Wd1hp = (uint4*)(ws + OFF_WD1H);
  uint4* Wd2ip = (uint4*)(ws + OFF_WD2I);
  uint4* Wd2hp = (uint4*)(ws + OFF_WD2H);
  uint4* Wmelp = (uint4*)(ws + OFF_WMEL);
  uint4* Wmp   = (uint4*)(ws + OFF_WM);
  unsigned* tpm  = (unsigned*)(ws + OFF_TPM);
  unsigned* encH = (unsigned*)(ws + OFF_ENCH);

  auto P = [&](const float* s, uint4* dst, int N, int K){
    int k8 = K/8, tot = N*k8;
    pack_w<<<(tot+255)/256, 256, 0, stream>>>(s, dst, N, k8);
  };
  P(W1, W1p, 256, 400);   P(W2, W2p, 128, 256);
  P(Wiha, Wihap, 768, 384); P(Whha, Whhap, 768, 256);
  P(Wq, Wqp, 256, 256);   P(Wm, Wmp, 256, 256);
  P(Wp, Wpp, 256, 512);
  P(Wd1i, Wd1ip, 768, 256); P(Wd1h, Wd1hp, 768, 256);
  P(Wd2i, Wd2ip, 768, 256); P(Wd2h, Wd2hp, 768, 256);
  P(Wmel, Wmelp, 400, 256);

  conv_enc<<<32768, 256, 0, stream>>>(enc, encH);
  pm_kernel<<<dim3(128,128), 1024, 0, stream>>>(enc, Wmp, tpm);
  prenet_kernel<<<dim3(200,128), 256, 0, stream>>>(inputs, b1, b2, W1p, W2p, (float*)d_out);

  decoder<<<64, 1024, 0, stream>>>(
      biha, bhha, v, bp, bd1i, bd1h, bd2i, bd2h,
      Wihap, Whhap, Wqp, Wpp, Wd1ip, Wd1hp, Wd2ip, Wd2hp,
      tpm, encH, (float*)d_out);

  mel_kernel<<<dim3(200,128), 512, 0, stream>>>(bmel, Wmelp, (float*)d_out);
}